// Round 1
// baseline (338.679 us; speedup 1.0000x reference)
//
#include <hip/hip_runtime.h>

#define B 32
#define C 512
#define TP 1024
#define CHUNK 64

// Kernel 1: per-batch inclusive cumsum of durations (1024 elements each).
__global__ void __launch_bounds__(TP) cumsum_k(const int* __restrict__ dur,
                                               int* __restrict__ cum) {
    __shared__ int s[TP];
    const int b = blockIdx.x;
    const int tid = threadIdx.x;
    s[tid] = dur[b * TP + tid];
    __syncthreads();
    // Hillis-Steele inclusive scan
    for (int off = 1; off < TP; off <<= 1) {
        int v = (tid >= off) ? s[tid - off] : 0;
        __syncthreads();
        s[tid] += v;
        __syncthreads();
    }
    cum[b * TP + tid] = s[tid];
}

// Kernel 2: for each (b, t) frame, binary-search the phone index once,
// then gather a chunk of 64 channels. Lane-consecutive t -> coalesced stores.
__global__ void __launch_bounds__(256) gather_k(const float* __restrict__ x,
                                                const int* __restrict__ cum,
                                                float* __restrict__ out,
                                                float* __restrict__ mask,
                                                int MF) {
    __shared__ int scum[TP];
    const int b = blockIdx.y;
    const int t = blockIdx.x * 256 + threadIdx.x;

    // cooperative load of this batch's cumsum into LDS (4 KB)
    for (int i = threadIdx.x; i < TP; i += 256) scum[i] = cum[b * TP + i];
    __syncthreads();

    if (t >= MF) return;

    const int total = scum[TP - 1];
    const bool valid = (t < total);

    // searchsorted(cum, t, side='right'): first index where cum[idx] > t
    int lo = 0, hi = TP;
    while (lo < hi) {
        int mid = (lo + hi) >> 1;
        if (scum[mid] <= t) lo = mid + 1; else hi = mid;
    }
    int p = lo < (TP - 1) ? lo : (TP - 1);

    if (blockIdx.z == 0) {
        mask[(size_t)b * MF + t] = valid ? 0.0f : 1.0f;  // mel_mask = ~valid
    }

    const float* xb = x   + ((size_t)b * C + (size_t)blockIdx.z * CHUNK) * TP;
    float*       ob = out + ((size_t)b * C + (size_t)blockIdx.z * CHUNK) * MF;

    if (valid) {
        #pragma unroll 4
        for (int c = 0; c < CHUNK; ++c)
            ob[(size_t)c * MF + t] = xb[(size_t)c * TP + p];
    } else {
        #pragma unroll 4
        for (int c = 0; c < CHUNK; ++c)
            ob[(size_t)c * MF + t] = 0.0f;
    }
}

extern "C" void kernel_launch(void* const* d_in, const int* in_sizes, int n_in,
                              void* d_out, int out_size, void* d_ws, size_t ws_size,
                              hipStream_t stream) {
    const float* x   = (const float*)d_in[0];
    const int*   dur = (const int*)d_in[1];
    float* out = (float*)d_out;

    // out_size = B*C*MF + B*MF = B*(C+1)*MF
    const int MF = out_size / (B * (C + 1));
    float* mask = out + (size_t)B * C * MF;

    int* cum = (int*)d_ws;  // B*TP int32 = 128 KB scratch

    cumsum_k<<<B, TP, 0, stream>>>(dur, cum);

    dim3 grid((MF + 255) / 256, B, C / CHUNK);
    gather_k<<<grid, 256, 0, stream>>>(x, cum, out, mask, MF);
}